// Round 9
// baseline (7851.834 us; speedup 1.0000x reference)
//
#include <hip/hip_runtime.h>
#include <hip/hip_fp16.h>
#include <cstdint>
#include <cstddef>

#define B_    256
#define T_    128
#define SIG_  64
#define MET_  32
#define H_    256
#define F_    16
#define NCOL  1040   // X cols: [i:0..255 | ste:256..511 | c:512..767 | o:768..1023 | fre:1024..1039]

// U is stored as 32 uint4 "chunks" per column-owner thread: chunk i of thread
// tid sits at U9[i*1024 + tid] (uint4), holding k = 8i..8i+7 of column
// c(tid) = ((tid&3)<<8) + (tid>>2).  Tier split:
//   chunks  0..11 : registers (48 VGPRs)            [needs LB(1024,1): R8
//                   proved LB(1024,4) caps VGPR at 64 and spills]
//   chunks 12..14 : LDS (48 KB)
//   chunks 15..31 : global stream (272 KB/CU/step, was 512 in R7)
#define NREG 12
#define NLDS 3
#define NGLB 17

__device__ __forceinline__ float hsig(float x) {
    return fminf(fmaxf(x * (1.0f/6.0f) + 0.5f, 0.0f), 1.0f);
}

__device__ __forceinline__ unsigned short f2h(float f) {
    __half h = __float2half(f);
    return *(unsigned short*)&h;
}

__device__ __forceinline__ float ntload_f(const float* p) {
    return __builtin_nontemporal_load(p);
}
__device__ __forceinline__ float4 ntload_f4(const float* p) {
    float4 v;
    v.x = __builtin_nontemporal_load(p + 0);
    v.y = __builtin_nontemporal_load(p + 1);
    v.z = __builtin_nontemporal_load(p + 2);
    v.w = __builtin_nontemporal_load(p + 3);
    return v;
}

typedef _Float16 half2v __attribute__((ext_vector_type(2)));

__device__ __forceinline__ float dot2(unsigned int u, unsigned int h, float acc) {
#if __has_builtin(__builtin_amdgcn_fdot2)
    return __builtin_amdgcn_fdot2(__builtin_bit_cast(half2v, u),
                                  __builtin_bit_cast(half2v, h), acc, false);
#else
    __half2 uu = *(__half2*)&u, hh = *(__half2*)&h;
    float2 uf = __half22float2(uu), hf = __half22float2(hh);
    return fmaf(uf.x, hf.x, fmaf(uf.y, hf.y, acc));
#endif
}

// ---------------------------------------------------------------------------
// Pack: Wcat[96][1040] f32, bcat[1040] f32,
// U9: fp16 chunked per-owner layout (see above), UF: fre cols [col][k].
// ---------------------------------------------------------------------------
__global__ __launch_bounds__(256) void pack_kernel(
    const float* __restrict__ Wis, const float* __restrict__ Wstes, const float* __restrict__ Wfres,
    const float* __restrict__ Wcs, const float* __restrict__ Wos,
    const float* __restrict__ Wim, const float* __restrict__ Wstem, const float* __restrict__ Wfrem,
    const float* __restrict__ Wcm, const float* __restrict__ Wom,
    const float* __restrict__ Ui, const float* __restrict__ Uste, const float* __restrict__ Ufre,
    const float* __restrict__ Uc, const float* __restrict__ Uo,
    const float* __restrict__ bi, const float* __restrict__ bste, const float* __restrict__ bfre,
    const float* __restrict__ bc, const float* __restrict__ bo,
    float* __restrict__ Wcat, float* __restrict__ bcat,
    unsigned short* __restrict__ U9, unsigned short* __restrict__ UF)
{
    int gtid = blockIdx.x * blockDim.x + threadIdx.x;
    int stride = gridDim.x * blockDim.x;
    const float* Wsig[5] = {Wis, Wstes, Wcs, Wos, Wfres};
    const float* Wmet[5] = {Wim, Wstem, Wcm, Wom, Wfrem};
    const float* Us[4]   = {Ui, Uste, Uc, Uo};
    const float* bs[5]   = {bi, bste, bc, bo, bfre};

    for (int i = gtid; i < 96*NCOL; i += stride) {
        int k = i / NCOL, n = i - k*NCOL;
        int sec, idx, secN;
        if (n < 1024) { sec = n >> 8; idx = n & 255; secN = H_; }
        else          { sec = 4; idx = n - 1024; secN = F_; }
        float v = (k < 64) ? Wsig[sec][k*secN + idx] : Wmet[sec][(k-64)*secN + idx];
        Wcat[k*NCOL + n] = v;
    }
    for (int n = gtid; n < NCOL; n += stride) {
        int sec, idx;
        if (n < 1024) { sec = n >> 8; idx = n & 255; }
        else          { sec = 4; idx = n - 1024; }
        bcat[n] = bs[sec][idx];
    }
    // main 1024 cols -> owner-thread chunk layout
    for (int i = gtid; i < 1024*H_; i += stride) {
        int col = i >> 8, k = i & 255;
        int g = col >> 8, j = col & 255;
        int tid = j * 4 + g;
        int chunk = k >> 3, e = k & 7;
        U9[(chunk * 1024 + tid) * 8 + e] = f2h(Us[g][k*H_ + j]);
    }
    // fre 16 cols
    for (int i = gtid; i < 16*H_; i += stride) {
        int col = i >> 8, k = i & 255;
        UF[col*H_ + k] = f2h(Ufre[k*F_ + col]);
    }
}

// ---------------------------------------------------------------------------
// Phase 1: input projection GEMM for ALL time steps.
// ---------------------------------------------------------------------------
__global__ __launch_bounds__(256) void proj_kernel(
    const float* __restrict__ sig, const float* __restrict__ met,
    const float* __restrict__ Wcat, const float* __restrict__ bcat,
    float* __restrict__ X)
{
    __shared__ float A_s[32][128];
    __shared__ float W_s[32][128];
    int tid = threadIdx.x;
    int c0b = blockIdx.x * 128;
    int m0  = blockIdx.y * 128;
    int t0  = blockIdx.z * 16;
    int r0  = (tid >> 4) * 8;
    int c0t = (tid & 15) * 8;

    float acc[8][8];
    #pragma unroll
    for (int i = 0; i < 8; ++i)
        #pragma unroll
        for (int j = 0; j < 8; ++j) acc[i][j] = 0.0f;

    for (int k0 = 0; k0 < 96; k0 += 32) {
        for (int idx = tid; idx < 32*128; idx += 256) {
            int ml = idx & 127, kk = idx >> 7;
            int m = m0 + ml;
            int b = m >> 4, tl = m & 15;
            int g = b * T_ + t0 + tl;
            int k = k0 + kk;
            float v = (k < 64) ? sig[g*SIG_ + k] : met[g*MET_ + (k - 64)];
            A_s[kk][ml] = v;
        }
        for (int idx = tid; idx < 32*128; idx += 256) {
            int c = idx & 127, kk = idx >> 7;
            int n = c0b + c;
            W_s[kk][c] = (n < NCOL) ? Wcat[(k0+kk)*NCOL + n] : 0.0f;
        }
        __syncthreads();
        #pragma unroll
        for (int kk = 0; kk < 32; ++kk) {
            float4 a0 = *(const float4*)&A_s[kk][r0];
            float4 a1 = *(const float4*)&A_s[kk][r0+4];
            float4 w0 = *(const float4*)&W_s[kk][c0t];
            float4 w1 = *(const float4*)&W_s[kk][c0t+4];
            float av[8] = {a0.x,a0.y,a0.z,a0.w,a1.x,a1.y,a1.z,a1.w};
            float wv[8] = {w0.x,w0.y,w0.z,w0.w,w1.x,w1.y,w1.z,w1.w};
            #pragma unroll
            for (int i = 0; i < 8; ++i)
                #pragma unroll
                for (int j = 0; j < 8; ++j)
                    acc[i][j] = fmaf(av[i], wv[j], acc[i][j]);
        }
        __syncthreads();
    }
    #pragma unroll
    for (int i = 0; i < 8; ++i) {
        int m = m0 + r0 + i;
        int bb = m >> 4, tl = m & 15;
        size_t row = (size_t)bb * T_ + t0 + tl;
        #pragma unroll
        for (int j = 0; j < 8; ++j) {
            int n = c0b + c0t + j;
            if (n < NCOL) X[row*NCOL + n] = acc[i][j] + bcat[n];
        }
    }
}

// ---------------------------------------------------------------------------
// Phase 2: full recurrence, SINGLE launch, grid=256 x 1024 threads.
// Thread tid owns FULL column ((tid&3)<<8)+(tid>>2): gate g=tid&3, row
// j=tid>>2. After its 256-k dot, the quad's 4 gate values are exchanged via
// __shfl(.,g,4) — no pre_s LDS round-trip, no extra barrier (intra-wave).
// U tiers: 12 chunks regs + 3 LDS + 17 global (272 KB/CU/step vs R7's 512).
// h reads are wave-uniform LDS broadcasts (R7-proven). fre cols: R7 scheme.
// LB(1024,1) — R8 proved LB(1024,4) force-caps VGPR at 64 and spills;
// invariants to check: VGPR ~100-120, WRITE_SIZE ~8 B.
// ---------------------------------------------------------------------------
__global__ __launch_bounds__(1024, 1) void recur_kernel(
    const float* __restrict__ X, const uint4* __restrict__ U9,
    const uint4* __restrict__ UF,
    const float* __restrict__ U_a, const float* __restrict__ b_a,
    const float* __restrict__ W_p, const float* __restrict__ b_p,
    const float* __restrict__ fc_w, const float* __restrict__ fc_b,
    float* __restrict__ out)
{
    __shared__ uint4 ldsU[NLDS * 1024];          // 49,152 B
    __shared__ float red_s[H_];                  //  1,024 B (head reduction)
    __shared__ unsigned int h_p[H_/2];           //    512 B (h as fp16 pairs)
    __shared__ float qp[64];                     //    256 B
    __shared__ float cs_s[16], sn_s[16];         //    128 B

    int tid  = threadIdx.x;
    int b    = blockIdx.x;
    int lane = tid & 63;
    int wid  = tid >> 6;
    bool isfre = ((lane & 15) == 15);
    int fq = lane >> 4;                  // quarter 0..3 (when isfre)

    int g  = tid & 3;                    // gate owned (i/ste/c/o)
    int j  = tid >> 2;                   // h row owned
    int f0 = g * 4;                      // f range owned in update

    // ---- register tier: chunks 0..11 of this thread's column ----
    uint4 ureg[NREG];
    #pragma unroll
    for (int i = 0; i < NREG; ++i) ureg[i] = U9[i * 1024 + tid];

    // ---- LDS tier: chunks 12..14 ----
    #pragma unroll
    for (int d = 0; d < NLDS; ++d)
        ldsU[d * 1024 + tid] = U9[(NREG + d) * 1024 + tid];

    if (tid < H_/2) h_p[tid] = 0u;
    if (tid < 16) {
        float ang = (float)tid * 0.39269908169872414f; // 2*pi/16
        cs_s[tid] = cosf(ang);
        sn_s[tid] = sinf(ang);
    }
    float Sre[4], Sim[4];
    #pragma unroll
    for (int r = 0; r < 4; ++r) { Sre[r] = 0.0f; Sim[r] = 0.0f; }

    float ba_j = b_a[j];
    float4 ua4 = ((const float4*)U_a)[g];
    const uint4* Ug = U9 + (NREG + NLDS) * 1024 + tid;   // global tier base
    const uint4* Uf = UF + (wid * 32 + fq * 8);          // fre quarter
    const float* Xb = X + (size_t)b * T_ * NCOL;
    __half* h_h = (__half*)h_p;
    int xoff = (g << 8) + j;             // this thread's x column

    float hnew = 0.0f;
    __syncthreads();

    for (int t = 0; t < T_; ++t) {
        const float* xrow = Xb + (size_t)t * NCOL;

        // ---- dot phase: acc = x[col] + U[:,col] . h  (3 ILP chains) ----
        float acc0 = ntload_f(&xrow[xoff]);
        float acc1 = 0.0f, acc2 = 0.0f;

        // global tier first so loads issue early
        #pragma unroll
        for (int i = 0; i < NGLB; ++i) {
            uint4 u  = Ug[i * 1024];
            uint4 hp = *(const uint4*)&h_p[(NREG + NLDS + i) * 4];
            acc2 = dot2(u.x, hp.x, acc2);
            acc2 = dot2(u.y, hp.y, acc2);
            acc2 = dot2(u.z, hp.z, acc2);
            acc2 = dot2(u.w, hp.w, acc2);
        }
        // register tier
        #pragma unroll
        for (int i = 0; i < NREG; ++i) {
            uint4 hp = *(const uint4*)&h_p[i * 4];
            acc0 = dot2(ureg[i].x, hp.x, acc0);
            acc0 = dot2(ureg[i].y, hp.y, acc0);
            acc0 = dot2(ureg[i].z, hp.z, acc0);
            acc0 = dot2(ureg[i].w, hp.w, acc0);
        }
        // LDS tier
        #pragma unroll
        for (int d = 0; d < NLDS; ++d) {
            uint4 u  = ldsU[d * 1024 + tid];
            uint4 hp = *(const uint4*)&h_p[(NREG + d) * 4];
            acc1 = dot2(u.x, hp.x, acc1);
            acc1 = dot2(u.y, hp.y, acc1);
            acc1 = dot2(u.z, hp.z, acc1);
            acc1 = dot2(u.w, hp.w, acc1);
        }
        float acc = acc0 + acc1 + acc2;

        float fa = 0.0f;
        if (isfre) {
            #pragma unroll
            for (int q = 0; q < 8; ++q) {
                uint4 u  = Uf[q];
                uint4 hp = *(const uint4*)&h_p[fq * 32 + q * 4];
                fa = dot2(u.x, hp.x, fa);
                fa = dot2(u.y, hp.y, fa);
                fa = dot2(u.z, hp.z, fa);
                fa = dot2(u.w, hp.w, fa);
            }
            qp[wid*4 + fq] = fa;
        }

        // ---- exchange gates within the quad (intra-wave, no barrier) ----
        float xi   = __shfl(acc, 0, 4);
        float xste = __shfl(acc, 1, 4);
        float xc   = __shfl(acc, 2, 4);
        float xo   = __shfl(acc, 3, 4);

        __syncthreads();   // A: qp ready; all h_p reads done

        // ---- update phase ----
        float gi   = hsig(xi);
        float gste = hsig(xste);
        float go   = hsig(xo);
        float cc   = gi * tanhf(xc);

        float4 xfre = ntload_f4(&xrow[1024 + f0]);
        float4 q0 = *(const float4*)&qp[(f0+0)*4];
        float4 q1 = *(const float4*)&qp[(f0+1)*4];
        float4 q2 = *(const float4*)&qp[(f0+2)*4];
        float4 q3 = *(const float4*)&qp[(f0+3)*4];
        float fre[4];
        fre[0] = hsig(xfre.x + q0.x + q0.y + q0.z + q0.w);
        fre[1] = hsig(xfre.y + q1.x + q1.y + q1.z + q1.w);
        fre[2] = hsig(xfre.z + q2.x + q2.y + q2.z + q2.w);
        fre[3] = hsig(xfre.w + q3.x + q3.y + q3.z + q3.w);

        int tt1 = (t + 1) & 15;
        float Aa = 0.0f;
        #pragma unroll
        for (int r = 0; r < 4; ++r) {
            int idx = (tt1 * (f0 + r)) & 15;
            float dec = gste * fre[r];
            float sre = fmaf(dec, Sre[r], cc * cs_s[idx]);
            float sim = fmaf(dec, Sim[r], cc * sn_s[idx]);
            Sre[r] = sre; Sim[r] = sim;
            Aa = fmaf(fmaf(sre, sre, sim*sim), ((const float*)&ua4)[r], Aa);
        }
        Aa += __shfl_xor(Aa, 1);
        Aa += __shfl_xor(Aa, 2);
        if (g == 0) {
            float a = tanhf(Aa + ba_j);
            hnew = go * a;
            h_h[j] = __float2half(hnew);
        }
        __syncthreads();   // B: h ready for next step
    }

    // ---- head: out[b] = (sum_j h[j]*W_p[j] + b_p)*fc_w + fc_b ----
    if (g == 0) red_s[j] = hnew * W_p[j];
    __syncthreads();
    for (int s = 128; s > 0; s >>= 1) {
        if (tid < s) red_s[tid] += red_s[tid + s];
        __syncthreads();
    }
    if (tid == 0) out[b] = (red_s[0] + b_p[0]) * fc_w[0] + fc_b[0];
}

// ---------------------------------------------------------------------------
extern "C" void kernel_launch(void* const* d_in, const int* in_sizes, int n_in,
                              void* d_out, int out_size, void* d_ws, size_t ws_size,
                              hipStream_t stream) {
    const float* signal = (const float*)d_in[0];
    const float* metmast = (const float*)d_in[1];
    const float* W_i_s   = (const float*)d_in[2];
    const float* W_ste_s = (const float*)d_in[3];
    const float* W_fre_s = (const float*)d_in[4];
    const float* W_c_s   = (const float*)d_in[5];
    const float* W_o_s   = (const float*)d_in[6];
    const float* W_i_m   = (const float*)d_in[7];
    const float* W_ste_m = (const float*)d_in[8];
    const float* W_fre_m = (const float*)d_in[9];
    const float* W_c_m   = (const float*)d_in[10];
    const float* W_o_m   = (const float*)d_in[11];
    const float* U_i   = (const float*)d_in[12];
    const float* b_i   = (const float*)d_in[13];
    const float* U_ste = (const float*)d_in[14];
    const float* b_ste = (const float*)d_in[15];
    const float* U_fre = (const float*)d_in[16];
    const float* b_fre = (const float*)d_in[17];
    const float* U_c   = (const float*)d_in[18];
    const float* b_c   = (const float*)d_in[19];
    const float* U_o   = (const float*)d_in[20];
    const float* b_o   = (const float*)d_in[21];
    const float* U_a   = (const float*)d_in[22];
    const float* b_a   = (const float*)d_in[23];
    const float* W_p   = (const float*)d_in[24];
    const float* b_p   = (const float*)d_in[25];
    const float* fc_w  = (const float*)d_in[26];
    const float* fc_b  = (const float*)d_in[27];
    float* out = (float*)d_out;

    char* ws = (char*)d_ws;
    float*          Wcat = (float*)(ws + 0);                 //  96*1040*4 = 399360
    float*          bcat = (float*)(ws + 399360);            //  4160 -> 403520
    unsigned short* U9   = (unsigned short*)(ws + 403520);   //  1024*256*2 = 524288 -> 927808
    unsigned short* UF   = (unsigned short*)(ws + 927808);   //  16*256*2 = 8192 -> 936000
    float*          X    = (float*)(ws + 936000);            //  256*128*1040*4 = 136314880
    // total ~137.3 MB

    pack_kernel<<<256, 256, 0, stream>>>(
        W_i_s, W_ste_s, W_fre_s, W_c_s, W_o_s,
        W_i_m, W_ste_m, W_fre_m, W_c_m, W_o_m,
        U_i, U_ste, U_fre, U_c, U_o,
        b_i, b_ste, b_fre, b_c, b_o,
        Wcat, bcat, U9, UF);

    proj_kernel<<<dim3(9, 32, 8), 256, 0, stream>>>(signal, metmast, Wcat, bcat, X);

    recur_kernel<<<B_, 1024, 0, stream>>>(X, (const uint4*)U9, (const uint4*)UF,
                                          U_a, b_a, W_p, b_p, fc_w, fc_b, out);
}

// Round 10
// 3022.168 us; speedup vs baseline: 2.5981x; 2.5981x over previous
//
#include <hip/hip_runtime.h>
#include <hip/hip_fp16.h>
#include <cstdint>
#include <cstddef>

#define B_    256
#define T_    128
#define SIG_  64
#define MET_  32
#define H_    256
#define F_    16
#define NCOL  1040   // X cols: [i:0..255 | ste:256..511 | c:512..767 | o:768..1023 | fre:1024..1039]

// recur: 512 threads/block, thread tid owns cols {tid, 512+tid}.
// U9 layout: 64 uint4 "slots" per thread; slot q = 2*(k>>3) + s, s = col>>9,
// holds k=8(q>>1)..+7 of col (s? 512+tid : tid). Address: U9u4[q*512 + tid].
// Tier split (per thread): q 0..39 registers (160 VGPRs), q 40..46 LDS
// (57 KB), q 47..63 global stream (272 B/thread/step = 139 KB/CU/step).
// R8/R9 lesson: 1024-thr blocks are HARD-CAPPED at 64 VGPRs by the compiler
// (LB 2nd arg ignored) -> register tiers spill. 512-thr blocks cap at 256.
#define QREG 40
#define QLDS 7
#define QGLB 17

__device__ __forceinline__ float hsig(float x) {
    return fminf(fmaxf(x * (1.0f/6.0f) + 0.5f, 0.0f), 1.0f);
}

__device__ __forceinline__ unsigned short f2h(float f) {
    __half h = __float2half(f);
    return *(unsigned short*)&h;
}

__device__ __forceinline__ float ntload_f(const float* p) {
    return __builtin_nontemporal_load(p);
}
__device__ __forceinline__ float4 ntload_f4(const float* p) {
    float4 v;
    v.x = __builtin_nontemporal_load(p + 0);
    v.y = __builtin_nontemporal_load(p + 1);
    v.z = __builtin_nontemporal_load(p + 2);
    v.w = __builtin_nontemporal_load(p + 3);
    return v;
}

typedef _Float16 half2v __attribute__((ext_vector_type(2)));

__device__ __forceinline__ float dot2(unsigned int u, unsigned int h, float acc) {
#if __has_builtin(__builtin_amdgcn_fdot2)
    return __builtin_amdgcn_fdot2(__builtin_bit_cast(half2v, u),
                                  __builtin_bit_cast(half2v, h), acc, false);
#else
    __half2 uu = *(__half2*)&u, hh = *(__half2*)&h;
    float2 uf = __half22float2(uu), hf = __half22float2(hh);
    return fmaf(uf.x, hf.x, fmaf(uf.y, hf.y, acc));
#endif
}

__device__ __forceinline__ float dot2x4(uint4 u, uint4 h, float acc) {
    acc = dot2(u.x, h.x, acc);
    acc = dot2(u.y, h.y, acc);
    acc = dot2(u.z, h.z, acc);
    acc = dot2(u.w, h.w, acc);
    return acc;
}

// ---------------------------------------------------------------------------
// Pack: Wcat[96][1040] f32, bcat[1040] f32, U9 (layout above), UF fre cols.
// ---------------------------------------------------------------------------
__global__ __launch_bounds__(256) void pack_kernel(
    const float* __restrict__ Wis, const float* __restrict__ Wstes, const float* __restrict__ Wfres,
    const float* __restrict__ Wcs, const float* __restrict__ Wos,
    const float* __restrict__ Wim, const float* __restrict__ Wstem, const float* __restrict__ Wfrem,
    const float* __restrict__ Wcm, const float* __restrict__ Wom,
    const float* __restrict__ Ui, const float* __restrict__ Uste, const float* __restrict__ Ufre,
    const float* __restrict__ Uc, const float* __restrict__ Uo,
    const float* __restrict__ bi, const float* __restrict__ bste, const float* __restrict__ bfre,
    const float* __restrict__ bc, const float* __restrict__ bo,
    float* __restrict__ Wcat, float* __restrict__ bcat,
    unsigned short* __restrict__ U9, unsigned short* __restrict__ UF)
{
    int gtid = blockIdx.x * blockDim.x + threadIdx.x;
    int stride = gridDim.x * blockDim.x;
    const float* Wsig[5] = {Wis, Wstes, Wcs, Wos, Wfres};
    const float* Wmet[5] = {Wim, Wstem, Wcm, Wom, Wfrem};
    const float* Us[4]   = {Ui, Uste, Uc, Uo};
    const float* bs[5]   = {bi, bste, bc, bo, bfre};

    for (int i = gtid; i < 96*NCOL; i += stride) {
        int k = i / NCOL, n = i - k*NCOL;
        int sec, idx, secN;
        if (n < 1024) { sec = n >> 8; idx = n & 255; secN = H_; }
        else          { sec = 4; idx = n - 1024; secN = F_; }
        float v = (k < 64) ? Wsig[sec][k*secN + idx] : Wmet[sec][(k-64)*secN + idx];
        Wcat[k*NCOL + n] = v;
    }
    for (int n = gtid; n < NCOL; n += stride) {
        int sec, idx;
        if (n < 1024) { sec = n >> 8; idx = n & 255; }
        else          { sec = 4; idx = n - 1024; }
        bcat[n] = bs[sec][idx];
    }
    // main 1024 cols -> owner-thread slot layout
    for (int i = gtid; i < 1024*H_; i += stride) {
        int col = i >> 8, k = i & 255;
        int g = col >> 8, j = col & 255;
        int tid = ((g & 1) << 8) + j;      // owner thread
        int s   = g >> 1;                  // which of its 2 cols
        int q   = ((k >> 3) << 1) | s;     // slot
        U9[(q * 512 + tid) * 8 + (k & 7)] = f2h(Us[g][k*H_ + j]);
    }
    // fre 16 cols: [col][k]
    for (int i = gtid; i < 16*H_; i += stride) {
        int col = i >> 8, k = i & 255;
        UF[col*H_ + k] = f2h(Ufre[k*F_ + col]);
    }
}

// ---------------------------------------------------------------------------
// Phase 1: input projection GEMM for ALL time steps.
// ---------------------------------------------------------------------------
__global__ __launch_bounds__(256) void proj_kernel(
    const float* __restrict__ sig, const float* __restrict__ met,
    const float* __restrict__ Wcat, const float* __restrict__ bcat,
    float* __restrict__ X)
{
    __shared__ float A_s[32][128];
    __shared__ float W_s[32][128];
    int tid = threadIdx.x;
    int c0b = blockIdx.x * 128;
    int m0  = blockIdx.y * 128;
    int t0  = blockIdx.z * 16;
    int r0  = (tid >> 4) * 8;
    int c0t = (tid & 15) * 8;

    float acc[8][8];
    #pragma unroll
    for (int i = 0; i < 8; ++i)
        #pragma unroll
        for (int j = 0; j < 8; ++j) acc[i][j] = 0.0f;

    for (int k0 = 0; k0 < 96; k0 += 32) {
        for (int idx = tid; idx < 32*128; idx += 256) {
            int ml = idx & 127, kk = idx >> 7;
            int m = m0 + ml;
            int b = m >> 4, tl = m & 15;
            int g = b * T_ + t0 + tl;
            int k = k0 + kk;
            float v = (k < 64) ? sig[g*SIG_ + k] : met[g*MET_ + (k - 64)];
            A_s[kk][ml] = v;
        }
        for (int idx = tid; idx < 32*128; idx += 256) {
            int c = idx & 127, kk = idx >> 7;
            int n = c0b + c;
            W_s[kk][c] = (n < NCOL) ? Wcat[(k0+kk)*NCOL + n] : 0.0f;
        }
        __syncthreads();
        #pragma unroll
        for (int kk = 0; kk < 32; ++kk) {
            float4 a0 = *(const float4*)&A_s[kk][r0];
            float4 a1 = *(const float4*)&A_s[kk][r0+4];
            float4 w0 = *(const float4*)&W_s[kk][c0t];
            float4 w1 = *(const float4*)&W_s[kk][c0t+4];
            float av[8] = {a0.x,a0.y,a0.z,a0.w,a1.x,a1.y,a1.z,a1.w};
            float wv[8] = {w0.x,w0.y,w0.z,w0.w,w1.x,w1.y,w1.z,w1.w};
            #pragma unroll
            for (int i = 0; i < 8; ++i)
                #pragma unroll
                for (int j = 0; j < 8; ++j)
                    acc[i][j] = fmaf(av[i], wv[j], acc[i][j]);
        }
        __syncthreads();
    }
    #pragma unroll
    for (int i = 0; i < 8; ++i) {
        int m = m0 + r0 + i;
        int bb = m >> 4, tl = m & 15;
        size_t row = (size_t)bb * T_ + t0 + tl;
        #pragma unroll
        for (int j = 0; j < 8; ++j) {
            int n = c0b + c0t + j;
            if (n < NCOL) X[row*NCOL + n] = acc[i][j] + bcat[n];
        }
    }
}

// ---------------------------------------------------------------------------
// Phase 2: full recurrence, SINGLE launch, grid=256 x 512 threads (8 waves).
// Dot: thread tid owns cols {tid, 512+tid}; h-chunk LDS reads shared by both
// cols (halves the R7 h-read traffic). fre: 8 lanes/wave ((lane&7)==7), wave
// w covers fre cols {2w, 2w+1} x 4 quarters -> qp[col*4+q].
// Update: 2 threads/row (hf = tid&1 owns f = 8*hf..8*hf+7; Sre[8]/Sim[8]),
// gates exchanged via pre_s, Aa via one shfl_xor(1).
// ---------------------------------------------------------------------------
__global__ __launch_bounds__(512, 1) __attribute__((amdgpu_waves_per_eu(1, 2)))
void recur_kernel(
    const float* __restrict__ X, const uint4* __restrict__ U9,
    const uint4* __restrict__ UF,
    const float* __restrict__ U_a, const float* __restrict__ b_a,
    const float* __restrict__ W_p, const float* __restrict__ b_p,
    const float* __restrict__ fc_w, const float* __restrict__ fc_b,
    float* __restrict__ out)
{
    __shared__ uint4 ldsU[QLDS * 512];           // 57,344 B
    __shared__ float pre_s[1024];                //  4,096 B (also head reduce)
    __shared__ uint4 h_p4[H_/8];                 //    512 B (h as fp16)
    __shared__ float qp[64];                     //    256 B
    __shared__ float cs_s[16], sn_s[16];         //    128 B  (total 62,336 B)

    int tid  = threadIdx.x;
    int b    = blockIdx.x;
    int lane = tid & 63;
    int wid  = tid >> 6;
    bool isfre = ((lane & 7) == 7);
    int fs = lane >> 3;                  // 0..7 (when isfre)
    int fcol = 2*wid + (fs >> 2);        // fre col 0..15
    int fq   = fs & 3;                   // quarter 0..3

    int j  = tid >> 1;                   // update row
    int hf = tid & 1;                    // update half: f = 8*hf + r

    // ---- register tier: slots 0..QREG-1 ----
    uint4 ureg[QREG];
    #pragma unroll
    for (int q = 0; q < QREG; ++q) ureg[q] = U9[q * 512 + tid];

    // ---- LDS tier: slots QREG..QREG+QLDS-1 ----
    #pragma unroll
    for (int d = 0; d < QLDS; ++d)
        ldsU[d * 512 + tid] = U9[(QREG + d) * 512 + tid];

    if (tid < H_/8) { uint4 z; z.x=z.y=z.z=z.w=0u; h_p4[tid] = z; }
    if (tid < 16) {
        float ang = (float)tid * 0.39269908169872414f; // 2*pi/16
        cs_s[tid] = cosf(ang);
        sn_s[tid] = sinf(ang);
    }
    float Sre[8], Sim[8];
    #pragma unroll
    for (int r = 0; r < 8; ++r) { Sre[r] = 0.0f; Sim[r] = 0.0f; }

    float ba_j = b_a[j];
    float4 ua_a = ((const float4*)U_a)[hf*2];
    float4 ua_b = ((const float4*)U_a)[hf*2 + 1];
    const uint4* Ug = U9 + (QREG + QLDS) * 512 + tid;  // global tier base
    const uint4* Uf = UF + (fcol * 32 + fq * 8);       // fre quarter
    const float* Xb = X + (size_t)b * T_ * NCOL;
    __half* h_h = (__half*)h_p4;

    float hnew = 0.0f;
    __syncthreads();

    for (int t = 0; t < T_; ++t) {
        const float* xrow = Xb + (size_t)t * NCOL;

        // ---- dot phase: acc0 = col tid, acc1 = col 512+tid ----
        float acc0 = ntload_f(&xrow[tid]);
        float acc1 = ntload_f(&xrow[512 + tid]);
        float accg = 0.0f;

        // global tier first so the 17 loads issue early (addresses fixed)
        #pragma unroll
        for (int q = QREG + QLDS; q < 64; ++q) {
            uint4 u  = Ug[(q - QREG - QLDS) * 512];
            uint4 hp = *(const uint4*)&h_p4[q >> 1];
            if (q & 1) acc1 = dot2x4(u, hp, acc1);
            else       accg = dot2x4(u, hp, accg);
        }
        // register tier: chunk c covers slots 2c (col0) and 2c+1 (col1)
        #pragma unroll
        for (int c = 0; c < QREG/2; ++c) {
            uint4 hp = h_p4[c];
            acc0 = dot2x4(ureg[2*c],     hp, acc0);
            acc1 = dot2x4(ureg[2*c + 1], hp, acc1);
        }
        // LDS tier
        #pragma unroll
        for (int d = 0; d < QLDS; ++d) {
            int q = QREG + d;
            uint4 u  = ldsU[d * 512 + tid];
            uint4 hp = h_p4[q >> 1];
            if (q & 1) acc1 = dot2x4(u, hp, acc1);
            else       acc0 = dot2x4(u, hp, acc0);
        }
        acc0 += accg;

        // fre columns (8 lanes/wave)
        if (isfre) {
            float fa = 0.0f;
            #pragma unroll
            for (int i = 0; i < 8; ++i)
                fa = dot2x4(Uf[i], h_p4[fq*8 + i], fa);
            qp[fcol*4 + fq] = fa;
        }

        pre_s[tid]       = acc0;
        pre_s[512 + tid] = acc1;
        __syncthreads();   // A: pre_s + qp ready; h reads done

        // ---- update phase: thread (j, hf) ----
        float xi   = pre_s[j];
        float xste = pre_s[256 + j];
        float xc   = pre_s[512 + j];
        float xo   = pre_s[768 + j];
        float gi   = hsig(xi);
        float gste = hsig(xste);
        float go   = hsig(xo);
        float cc   = gi * tanhf(xc);

        float4 xf0 = ntload_f4(&xrow[1024 + hf*8]);
        float4 xf1 = ntload_f4(&xrow[1024 + hf*8 + 4]);
        float xfre[8] = {xf0.x,xf0.y,xf0.z,xf0.w,xf1.x,xf1.y,xf1.z,xf1.w};

        int tt1 = (t + 1) & 15;
        float Aa = 0.0f;
        #pragma unroll
        for (int r = 0; r < 8; ++r) {
            int f = hf*8 + r;
            float4 q4 = *(const float4*)&qp[f*4];
            float fre = hsig(xfre[r] + q4.x + q4.y + q4.z + q4.w);
            int idx = (tt1 * f) & 15;
            float dec = gste * fre;
            float sre = fmaf(dec, Sre[r], cc * cs_s[idx]);
            float sim = fmaf(dec, Sim[r], cc * sn_s[idx]);
            Sre[r] = sre; Sim[r] = sim;
            float ua = (r < 4) ? ((const float*)&ua_a)[r] : ((const float*)&ua_b)[r-4];
            Aa = fmaf(fmaf(sre, sre, sim*sim), ua, Aa);
        }
        Aa += __shfl_xor(Aa, 1);
        if (hf == 0) {
            float a = tanhf(Aa + ba_j);
            hnew = go * a;
            h_h[j] = __float2half(hnew);
        }
        __syncthreads();   // B: h ready for next step; pre_s/qp reads done
    }

    // ---- head: out[b] = (sum_j h[j]*W_p[j] + b_p)*fc_w + fc_b ----
    if (hf == 0) pre_s[j] = hnew * W_p[j];
    __syncthreads();
    for (int s = 128; s > 0; s >>= 1) {
        if (tid < s) pre_s[tid] += pre_s[tid + s];
        __syncthreads();
    }
    if (tid == 0) out[b] = (pre_s[0] + b_p[0]) * fc_w[0] + fc_b[0];
}

// ---------------------------------------------------------------------------
extern "C" void kernel_launch(void* const* d_in, const int* in_sizes, int n_in,
                              void* d_out, int out_size, void* d_ws, size_t ws_size,
                              hipStream_t stream) {
    const float* signal = (const float*)d_in[0];
    const float* metmast = (const float*)d_in[1];
    const float* W_i_s   = (const float*)d_in[2];
    const float* W_ste_s = (const float*)d_in[3];
    const float* W_fre_s = (const float*)d_in[4];
    const float* W_c_s   = (const float*)d_in[5];
    const float* W_o_s   = (const float*)d_in[6];
    const float* W_i_m   = (const float*)d_in[7];
    const float* W_ste_m = (const float*)d_in[8];
    const float* W_fre_m = (const float*)d_in[9];
    const float* W_c_m   = (const float*)d_in[10];
    const float* W_o_m   = (const float*)d_in[11];
    const float* U_i   = (const float*)d_in[12];
    const float* b_i   = (const float*)d_in[13];
    const float* U_ste = (const float*)d_in[14];
    const float* b_ste = (const float*)d_in[15];
    const float* U_fre = (const float*)d_in[16];
    const float* b_fre = (const float*)d_in[17];
    const float* U_c   = (const float*)d_in[18];
    const float* b_c   = (const float*)d_in[19];
    const float* U_o   = (const float*)d_in[20];
    const float* b_o   = (const float*)d_in[21];
    const float* U_a   = (const float*)d_in[22];
    const float* b_a   = (const float*)d_in[23];
    const float* W_p   = (const float*)d_in[24];
    const float* b_p   = (const float*)d_in[25];
    const float* fc_w  = (const float*)d_in[26];
    const float* fc_b  = (const float*)d_in[27];
    float* out = (float*)d_out;

    char* ws = (char*)d_ws;
    float*          Wcat = (float*)(ws + 0);                 //  96*1040*4 = 399360
    float*          bcat = (float*)(ws + 399360);            //  4160 -> 403520
    unsigned short* U9   = (unsigned short*)(ws + 403520);   //  64*512*8*2 = 524288 -> 927808
    unsigned short* UF   = (unsigned short*)(ws + 927808);   //  16*256*2 = 8192 -> 936000
    float*          X    = (float*)(ws + 936000);            //  256*128*1040*4 = 136314880
    // total ~137.3 MB

    pack_kernel<<<256, 256, 0, stream>>>(
        W_i_s, W_ste_s, W_fre_s, W_c_s, W_o_s,
        W_i_m, W_ste_m, W_fre_m, W_c_m, W_o_m,
        U_i, U_ste, U_fre, U_c, U_o,
        b_i, b_ste, b_fre, b_c, b_o,
        Wcat, bcat, U9, UF);

    proj_kernel<<<dim3(9, 32, 8), 256, 0, stream>>>(signal, metmast, Wcat, bcat, X);

    recur_kernel<<<B_, 512, 0, stream>>>(X, (const uint4*)U9, (const uint4*)UF,
                                         U_a, b_a, W_p, b_p, fc_w, fc_b, out);
}

// Round 11
// 1073.884 us; speedup vs baseline: 7.3116x; 2.8142x over previous
//
#include <hip/hip_runtime.h>
#include <hip/hip_fp16.h>
#include <cstdint>
#include <cstddef>

#define B_    256
#define T_    128
#define SIG_  64
#define MET_  32
#define H_    256
#define F_    16
#define NCOL  1040   // X cols: [i:0..255 | ste:256..511 | c:512..767 | o:768..1023 | fre:1024..1039]

#define NLDS  3      // U slots staged in LDS (48 KB); slots NLDS..31 streamed

__device__ __forceinline__ float hsig(float x) {
    return fminf(fmaxf(x * (1.0f/6.0f) + 0.5f, 0.0f), 1.0f);
}

__device__ __forceinline__ unsigned short f2h(float f) {
    __half h = __float2half(f);
    return *(unsigned short*)&h;
}

__device__ __forceinline__ float ntload_f(const float* p) {
    return __builtin_nontemporal_load(p);
}
__device__ __forceinline__ float4 ntload_f4(const float* p) {
    float4 v;
    v.x = __builtin_nontemporal_load(p + 0);
    v.y = __builtin_nontemporal_load(p + 1);
    v.z = __builtin_nontemporal_load(p + 2);
    v.w = __builtin_nontemporal_load(p + 3);
    return v;
}

// Workgroup barrier WITHOUT the vmcnt(0) drain __syncthreads() forces.
// lgkmcnt(0) makes all LDS writes visible before s_barrier (LDS has no
// cache, so that is sufficient for intra-block LDS coherence). Pending
// GLOBAL loads stay in flight across the barrier — safe here because the
// streamed U values are step-invariant (written once by pack_kernel).
__device__ __forceinline__ void lbar() {
    asm volatile("s_waitcnt lgkmcnt(0)\n\ts_barrier" ::: "memory");
}

typedef _Float16 half2v __attribute__((ext_vector_type(2)));

__device__ __forceinline__ float dot2(unsigned int u, unsigned int h, float acc) {
#if __has_builtin(__builtin_amdgcn_fdot2)
    return __builtin_amdgcn_fdot2(__builtin_bit_cast(half2v, u),
                                  __builtin_bit_cast(half2v, h), acc, false);
#else
    __half2 uu = *(__half2*)&u, hh = *(__half2*)&h;
    float2 uf = __half22float2(uu), hf = __half22float2(hh);
    return fmaf(uf.x, hf.x, fmaf(uf.y, hf.y, acc));
#endif
}

__device__ __forceinline__ float dot2x4(uint4 u, uint4 h, float acc) {
    acc = dot2(u.x, h.x, acc);
    acc = dot2(u.y, h.y, acc);
    acc = dot2(u.z, h.z, acc);
    acc = dot2(u.w, h.w, acc);
    return acc;
}

// ---------------------------------------------------------------------------
// Pack: Wcat[96][1040] f32, bcat[1040] f32,
// U8: fp16 main cols, [k8][col] uint4 — slot kk at U8[kk*1024+col] holds
//     k=8kk..8kk+7 of col. Wave reads: 16 B/lane, 1 KB contiguous.
// UF: fp16 fre cols, [col][k] (8 KB, L1-resident).
// ---------------------------------------------------------------------------
__global__ __launch_bounds__(256) void pack_kernel(
    const float* __restrict__ Wis, const float* __restrict__ Wstes, const float* __restrict__ Wfres,
    const float* __restrict__ Wcs, const float* __restrict__ Wos,
    const float* __restrict__ Wim, const float* __restrict__ Wstem, const float* __restrict__ Wfrem,
    const float* __restrict__ Wcm, const float* __restrict__ Wom,
    const float* __restrict__ Ui, const float* __restrict__ Uste, const float* __restrict__ Ufre,
    const float* __restrict__ Uc, const float* __restrict__ Uo,
    const float* __restrict__ bi, const float* __restrict__ bste, const float* __restrict__ bfre,
    const float* __restrict__ bc, const float* __restrict__ bo,
    float* __restrict__ Wcat, float* __restrict__ bcat,
    unsigned short* __restrict__ U8, unsigned short* __restrict__ UF)
{
    int gtid = blockIdx.x * blockDim.x + threadIdx.x;
    int stride = gridDim.x * blockDim.x;
    const float* Wsig[5] = {Wis, Wstes, Wcs, Wos, Wfres};
    const float* Wmet[5] = {Wim, Wstem, Wcm, Wom, Wfrem};
    const float* Us[4]   = {Ui, Uste, Uc, Uo};
    const float* bs[5]   = {bi, bste, bc, bo, bfre};

    for (int i = gtid; i < 96*NCOL; i += stride) {
        int k = i / NCOL, n = i - k*NCOL;
        int sec, idx, secN;
        if (n < 1024) { sec = n >> 8; idx = n & 255; secN = H_; }
        else          { sec = 4; idx = n - 1024; secN = F_; }
        float v = (k < 64) ? Wsig[sec][k*secN + idx] : Wmet[sec][(k-64)*secN + idx];
        Wcat[k*NCOL + n] = v;
    }
    for (int n = gtid; n < NCOL; n += stride) {
        int sec, idx;
        if (n < 1024) { sec = n >> 8; idx = n & 255; }
        else          { sec = 4; idx = n - 1024; }
        bcat[n] = bs[sec][idx];
    }
    // main 1024 cols
    for (int i = gtid; i < 1024*H_; i += stride) {
        int col = i >> 8, k = i & 255;
        int sec = col >> 8, idx = col & 255;
        U8[(((k >> 3) * 1024) + col) * 8 + (k & 7)] = f2h(Us[sec][k*H_ + idx]);
    }
    // fre 16 cols
    for (int i = gtid; i < 16*H_; i += stride) {
        int col = i >> 8, k = i & 255;
        UF[col*H_ + k] = f2h(Ufre[k*F_ + col]);
    }
}

// ---------------------------------------------------------------------------
// Phase 1: input projection GEMM for ALL time steps.
// ---------------------------------------------------------------------------
__global__ __launch_bounds__(256) void proj_kernel(
    const float* __restrict__ sig, const float* __restrict__ met,
    const float* __restrict__ Wcat, const float* __restrict__ bcat,
    float* __restrict__ X)
{
    __shared__ float A_s[32][128];
    __shared__ float W_s[32][128];
    int tid = threadIdx.x;
    int c0b = blockIdx.x * 128;
    int m0  = blockIdx.y * 128;
    int t0  = blockIdx.z * 16;
    int r0  = (tid >> 4) * 8;
    int c0t = (tid & 15) * 8;

    float acc[8][8];
    #pragma unroll
    for (int i = 0; i < 8; ++i)
        #pragma unroll
        for (int j = 0; j < 8; ++j) acc[i][j] = 0.0f;

    for (int k0 = 0; k0 < 96; k0 += 32) {
        for (int idx = tid; idx < 32*128; idx += 256) {
            int ml = idx & 127, kk = idx >> 7;
            int m = m0 + ml;
            int b = m >> 4, tl = m & 15;
            int g = b * T_ + t0 + tl;
            int k = k0 + kk;
            float v = (k < 64) ? sig[g*SIG_ + k] : met[g*MET_ + (k - 64)];
            A_s[kk][ml] = v;
        }
        for (int idx = tid; idx < 32*128; idx += 256) {
            int c = idx & 127, kk = idx >> 7;
            int n = c0b + c;
            W_s[kk][c] = (n < NCOL) ? Wcat[(k0+kk)*NCOL + n] : 0.0f;
        }
        __syncthreads();
        #pragma unroll
        for (int kk = 0; kk < 32; ++kk) {
            float4 a0 = *(const float4*)&A_s[kk][r0];
            float4 a1 = *(const float4*)&A_s[kk][r0+4];
            float4 w0 = *(const float4*)&W_s[kk][c0t];
            float4 w1 = *(const float4*)&W_s[kk][c0t+4];
            float av[8] = {a0.x,a0.y,a0.z,a0.w,a1.x,a1.y,a1.z,a1.w};
            float wv[8] = {w0.x,w0.y,w0.z,w0.w,w1.x,w1.y,w1.z,w1.w};
            #pragma unroll
            for (int i = 0; i < 8; ++i)
                #pragma unroll
                for (int j = 0; j < 8; ++j)
                    acc[i][j] = fmaf(av[i], wv[j], acc[i][j]);
        }
        __syncthreads();
    }
    #pragma unroll
    for (int i = 0; i < 8; ++i) {
        int m = m0 + r0 + i;
        int bb = m >> 4, tl = m & 15;
        size_t row = (size_t)bb * T_ + t0 + tl;
        #pragma unroll
        for (int j = 0; j < 8; ++j) {
            int n = c0b + c0t + j;
            if (n < NCOL) X[row*NCOL + n] = acc[i][j] + bcat[n];
        }
    }
}

// ---------------------------------------------------------------------------
// Phase 2: full recurrence, SINGLE launch, grid=256 x 1024 threads (R7 base,
// 836 us). R11 changes:
//  (1) U slots 0..2 staged in LDS once (48 KB) -> streamed bytes/step -9.4%.
//  (2) in-loop barriers are lgkm-only (lbar) -> no vmcnt(0) drain; global U
//      loads pipeline across steps (they are step-invariant, so this is
//      safe). Discriminates latency-exposure vs port-bound theories.
// NO register U tier: VGPR cap = 65536/blockDim (measured R8-R10); at 1024
// threads the cap is 64 and any tier spills (WRITE_SIZE explosion).
// ---------------------------------------------------------------------------
__global__ __launch_bounds__(1024) void recur_kernel(
    const float* __restrict__ X, const uint4* __restrict__ U8,
    const uint4* __restrict__ UF,
    const float* __restrict__ U_a, const float* __restrict__ b_a,
    const float* __restrict__ W_p, const float* __restrict__ b_p,
    const float* __restrict__ fc_w, const float* __restrict__ fc_b,
    float* __restrict__ out)
{
    __shared__ uint4 ldsU[NLDS * 1024];  // 49,152 B
    __shared__ float pre_s[1024];        //  4,096 B
    __shared__ uint4 h_p4[H_/8];         //    512 B (h as fp16 pairs)
    __shared__ float qp[64];             //    256 B (fre quarter partials)
    __shared__ float cs_s[16], sn_s[16]; //    128 B   (total 54,144 B)

    int tid  = threadIdx.x;
    int b    = blockIdx.x;
    int lane = tid & 63;
    int wid  = tid >> 6;
    bool isfre = ((lane & 15) == 15);
    int fq = lane >> 4;                  // quarter 0..3 (when isfre)

    // update-phase ownership: j = tid>>2 (h row), f0 = (tid&3)*4 (f range)
    int j  = tid >> 2;
    int f0 = (tid & 3) * 4;

    // stage LDS U tier (slots 0..NLDS-1)
    #pragma unroll
    for (int d = 0; d < NLDS; ++d)
        ldsU[d * 1024 + tid] = U8[d * 1024 + tid];

    if (tid < H_/8) { uint4 z; z.x=z.y=z.z=z.w=0u; h_p4[tid] = z; }
    if (tid < 16) {
        float ang = (float)tid * 0.39269908169872414f; // 2*pi/16
        cs_s[tid] = cosf(ang);
        sn_s[tid] = sinf(ang);
    }
    float Sre[4], Sim[4];
    #pragma unroll
    for (int r = 0; r < 4; ++r) { Sre[r] = 0.0f; Sim[r] = 0.0f; }

    float ba_j = b_a[j];
    float4 ua4 = ((const float4*)U_a)[tid & 3];
    const uint4* Uf = UF + (wid * 32 + fq * 8);   // quarter fq of fre col wid
    const float* Xb = X + (size_t)b * T_ * NCOL;
    __half* h_h = (__half*)h_p4;

    float hnew = 0.0f;
    __syncthreads();

    for (int t = 0; t < T_; ++t) {
        const float* xrow = Xb + (size_t)t * NCOL;

        // ---- dot phase: pre[col=tid] = x + U[:,col] . h ----
        float acc = ntload_f(&xrow[tid]);
        // global tier (slots NLDS..31): loads pipeline across lbar()
        #pragma unroll 8
        for (int kk = NLDS; kk < 32; ++kk) {
            uint4 u = U8[kk * 1024 + tid];
            acc = dot2x4(u, h_p4[kk], acc);
        }
        // LDS tier (slots 0..NLDS-1); h_p4 reads are wave-uniform broadcasts
        #pragma unroll
        for (int d = 0; d < NLDS; ++d) {
            uint4 u = ldsU[d * 1024 + tid];
            acc = dot2x4(u, h_p4[d], acc);
        }
        float fa = 0.0f;
        if (isfre) {
            #pragma unroll
            for (int q = 0; q < 8; ++q)
                fa = dot2x4(Uf[q], h_p4[fq * 8 + q], fa);
        }
        pre_s[tid] = acc;
        if (isfre) qp[wid*4 + fq] = fa;
        lbar();   // A: pre_s + qp visible; h_p4 reads done (lgkm only)

        // ---- update phase ----
        float xi   = pre_s[j];
        float xste = pre_s[256 + j];
        float xc   = pre_s[512 + j];
        float xo   = pre_s[768 + j];
        float gi   = hsig(xi);
        float gste = hsig(xste);
        float go   = hsig(xo);
        float cc   = gi * tanhf(xc);

        float4 xfre = ntload_f4(&xrow[1024 + f0]);
        float4 q0 = *(const float4*)&qp[(f0+0)*4];
        float4 q1 = *(const float4*)&qp[(f0+1)*4];
        float4 q2 = *(const float4*)&qp[(f0+2)*4];
        float4 q3 = *(const float4*)&qp[(f0+3)*4];
        float fre[4];
        fre[0] = hsig(xfre.x + q0.x + q0.y + q0.z + q0.w);
        fre[1] = hsig(xfre.y + q1.x + q1.y + q1.z + q1.w);
        fre[2] = hsig(xfre.z + q2.x + q2.y + q2.z + q2.w);
        fre[3] = hsig(xfre.w + q3.x + q3.y + q3.z + q3.w);

        int tt1 = (t + 1) & 15;
        float Aa = 0.0f;
        #pragma unroll
        for (int r = 0; r < 4; ++r) {
            int idx = (tt1 * (f0 + r)) & 15;
            float dec = gste * fre[r];
            float sre = fmaf(dec, Sre[r], cc * cs_s[idx]);
            float sim = fmaf(dec, Sim[r], cc * sn_s[idx]);
            Sre[r] = sre; Sim[r] = sim;
            Aa = fmaf(fmaf(sre, sre, sim*sim), ((const float*)&ua4)[r], Aa);
        }
        Aa += __shfl_xor(Aa, 1);
        Aa += __shfl_xor(Aa, 2);
        if ((tid & 3) == 0) {
            float a = tanhf(Aa + ba_j);
            hnew = go * a;
            h_h[j] = __float2half(hnew);
        }
        lbar();   // B: h visible for next step (lgkm only)
    }

    // ---- head: out[b] = (sum_j h[j]*W_p[j] + b_p)*fc_w + fc_b ----
    if ((tid & 3) == 0) pre_s[j] = hnew * W_p[j];
    __syncthreads();
    for (int s = 128; s > 0; s >>= 1) {
        if (tid < s) pre_s[tid] += pre_s[tid + s];
        __syncthreads();
    }
    if (tid == 0) out[b] = (pre_s[0] + b_p[0]) * fc_w[0] + fc_b[0];
}

// ---------------------------------------------------------------------------
extern "C" void kernel_launch(void* const* d_in, const int* in_sizes, int n_in,
                              void* d_out, int out_size, void* d_ws, size_t ws_size,
                              hipStream_t stream) {
    const float* signal = (const float*)d_in[0];
    const float* metmast = (const float*)d_in[1];
    const float* W_i_s   = (const float*)d_in[2];
    const float* W_ste_s = (const float*)d_in[3];
    const float* W_fre_s = (const float*)d_in[4];
    const float* W_c_s   = (const float*)d_in[5];
    const float* W_o_s   = (const float*)d_in[6];
    const float* W_i_m   = (const float*)d_in[7];
    const float* W_ste_m = (const float*)d_in[8];
    const float* W_fre_m = (const float*)d_in[9];
    const float* W_c_m   = (const float*)d_in[10];
    const float* W_o_m   = (const float*)d_in[11];
    const float* U_i   = (const float*)d_in[12];
    const float* b_i   = (const float*)d_in[13];
    const float* U_ste = (const float*)d_in[14];
    const float* b_ste = (const float*)d_in[15];
    const float* U_fre = (const float*)d_in[16];
    const float* b_fre = (const float*)d_in[17];
    const float* U_c   = (const float*)d_in[18];
    const float* b_c   = (const float*)d_in[19];
    const float* U_o   = (const float*)d_in[20];
    const float* b_o   = (const float*)d_in[21];
    const float* U_a   = (const float*)d_in[22];
    const float* b_a   = (const float*)d_in[23];
    const float* W_p   = (const float*)d_in[24];
    const float* b_p   = (const float*)d_in[25];
    const float* fc_w  = (const float*)d_in[26];
    const float* fc_b  = (const float*)d_in[27];
    float* out = (float*)d_out;

    char* ws = (char*)d_ws;
    float*          Wcat = (float*)(ws + 0);                 //  96*1040*4 = 399360
    float*          bcat = (float*)(ws + 399360);            //  4160 -> 403520
    unsigned short* U8   = (unsigned short*)(ws + 403520);   //  1024*256*2 = 524288 -> 927808
    unsigned short* UF   = (unsigned short*)(ws + 927808);   //  16*256*2 = 8192 -> 936000
    float*          X    = (float*)(ws + 936000);            //  256*128*1040*4 = 136314880
    // total ~137.3 MB

    pack_kernel<<<256, 256, 0, stream>>>(
        W_i_s, W_ste_s, W_fre_s, W_c_s, W_o_s,
        W_i_m, W_ste_m, W_fre_m, W_c_m, W_o_m,
        U_i, U_ste, U_fre, U_c, U_o,
        b_i, b_ste, b_fre, b_c, b_o,
        Wcat, bcat, U8, UF);

    proj_kernel<<<dim3(9, 32, 8), 256, 0, stream>>>(signal, metmast, Wcat, bcat, X);

    recur_kernel<<<B_, 1024, 0, stream>>>(X, (const uint4*)U8, (const uint4*)UF,
                                          U_a, b_a, W_p, b_p, fc_w, fc_b, out);
}